// Round 9
// baseline (300.956 us; speedup 1.0000x reference)
//
#include <hip/hip_runtime.h>

#define N_NODES 100000
#define N_EDGES 600000
#define DIM 128
#define NUM_RELS 8
#define NBINS (NUM_RELS * N_NODES)          // node-major: key = dst*8 + r
#define SCAN_NB ((NBINS + 1023) / 1024)     // 782
#define XBLOCKS 6250
#define TBLOCKS 576
#define HBLOCKS ((N_EDGES + 255) / 256)

#define RPB 16                               // dsts per fused block
#define BPB (RPB * NUM_RELS)                 // 128 bins/block
#define FBLOCKS (N_NODES / RPB)              // 6250 exact
#define LDS_BYTES ((BPB * 64 + 132) * 4)     // 33,296 B -> 4 blocks/CU

typedef unsigned int u32;
typedef __attribute__((ext_vector_type(8))) short bf16x8;
typedef __attribute__((ext_vector_type(4))) float f32x4;

__device__ __forceinline__ u32 pack2_bf16_rn(float lo, float hi) {
    u32 a = __float_as_uint(lo);
    u32 b = __float_as_uint(hi);
    a += 0x7fffu + ((a >> 16) & 1u);
    b += 0x7fffu + ((b >> 16) & 1u);
    return (a >> 16) | (b & 0xffff0000u);
}

// ---------------------------------------------------------------------------
// prep = convert_x | transpose_w | hist+rank
__global__ __launch_bounds__(256) void prep(
    const float* __restrict__ x, uint4* __restrict__ x_bf,
    const float* __restrict__ W, const float* __restrict__ W_root,
    unsigned short* __restrict__ Wt,
    const int* __restrict__ ei, const int* __restrict__ et,
    u32* __restrict__ hist, u32* __restrict__ rank) {
    int b = blockIdx.x, tid = threadIdx.x;
    if (b < XBLOCKS) {
        int t = b * 256 + tid;
        const float4* p = reinterpret_cast<const float4*>(x) + (size_t)t * 2;
        float4 v0 = p[0], v1 = p[1];
        uint4 o;
        o.x = pack2_bf16_rn(v0.x, v0.y);
        o.y = pack2_bf16_rn(v0.z, v0.w);
        o.z = pack2_bf16_rn(v1.x, v1.y);
        o.w = pack2_bf16_rn(v1.z, v1.w);
        x_bf[t] = o;
    } else if (b < XBLOCKS + TBLOCKS) {
        int t = (b - XBLOCKS) * 256 + tid;
        int c  = t >> 14;
        int kn = t & 16383;
        int k = kn >> 7, n = kn & 127;
        float v = (c == 0) ? W_root[kn] : W[(size_t)(c - 1) * DIM * DIM + kn];
        u32 bb = __float_as_uint(v);
        bb += 0x7fffu + ((bb >> 16) & 1u);
        Wt[(size_t)c * 16384 + n * 128 + k] = (unsigned short)(bb >> 16);
    } else {
        int e = (b - XBLOCKS - TBLOCKS) * 256 + tid;
        if (e < N_EDGES) {
            int dst = ei[N_EDGES + e];
            int r   = et[e];
            rank[e] = atomicAdd(&hist[(size_t)dst * NUM_RELS + r], 1u);
        }
    }
}

// ---------------------------------------------------------------------------
// scanA: block-local exclusive prefix of hist -> locpre, block totals -> bsum
__global__ __launch_bounds__(256) void scanA(const u32* __restrict__ hist,
                                             u32* __restrict__ locpre,
                                             u32* __restrict__ bsum) {
    __shared__ u32 sh[256];
    int t = threadIdx.x;
    size_t base = (size_t)blockIdx.x * 1024 + t * 4;
    u32 v[4]; u32 s = 0;
#pragma unroll
    for (int j = 0; j < 4; ++j) { size_t i = base + j; v[j] = (i < NBINS) ? hist[i] : 0; s += v[j]; }
    sh[t] = s; __syncthreads();
    for (int off = 1; off < 256; off <<= 1) {
        u32 add = (t >= off) ? sh[t - off] : 0;
        __syncthreads();
        sh[t] += add;
        __syncthreads();
    }
    u32 run = (t > 0) ? sh[t - 1] : 0;
#pragma unroll
    for (int j = 0; j < 4; ++j) {
        size_t i = base + j;
        if (i < NBINS) locpre[i] = run;
        run += v[j];
    }
    if (t == 255) bsum[blockIdx.x] = sh[255];
}

// scanB: 1-block exclusive scan of the 782 block totals
__global__ __launch_bounds__(256) void scanB(u32* __restrict__ bsum, int nb) {
    __shared__ u32 sh[256];
    int t = threadIdx.x;
    u32 v[4]; u32 s = 0;
#pragma unroll
    for (int j = 0; j < 4; ++j) { int i = t * 4 + j; v[j] = (i < nb) ? bsum[i] : 0; s += v[j]; }
    sh[t] = s; __syncthreads();
    for (int off = 1; off < 256; off <<= 1) {
        u32 add = (t >= off) ? sh[t - off] : 0;
        __syncthreads();
        sh[t] += add;
        __syncthreads();
    }
    u32 run = (t > 0) ? sh[t - 1] : 0;
#pragma unroll
    for (int j = 0; j < 4; ++j) { int i = t * 4 + j; if (i < nb) bsum[i] = run; run += v[j]; }
}

// pos = locpre[key] + bsumx[key>>10] + rank; spk = src | local_bin<<17
__global__ __launch_bounds__(256) void reorder(const int* __restrict__ ei,
                                               const int* __restrict__ et,
                                               const u32* __restrict__ locpre,
                                               const u32* __restrict__ bsumx,
                                               const u32* __restrict__ rank,
                                               u32* __restrict__ spk) {
    int e = blockIdx.x * 256 + threadIdx.x;
    if (e >= N_EDGES) return;
    int dst = ei[N_EDGES + e];
    int r   = et[e];
    size_t key = (size_t)dst * NUM_RELS + r;
    u32 pos = locpre[key] + bsumx[key >> 10] + rank[e];
    u32 bin = (u32)((dst & (RPB - 1)) * NUM_RELS + r);
    spk[pos] = (u32)ei[e] | (bin << 17);
}

// ---------------------------------------------------------------------------
// write mean row (bf16-packed, granule-XOR-swizzled) for the finished bin
#define FLUSH2() do { \
    float sc_ = __builtin_amdgcn_rcpf((float)rcnt); \
    ACC[(u32)cur_bin * 64u + ((((lane >> 2) ^ (((u32)cur_bin >> 3) & 15u)) << 2) | (u32)(lane & 3))] = \
        pack2_bf16_rn(a0 * sc_, a1 * sc_); \
} while (0)

// Fused RGCN: sorted-run register aggregation into 32KB LDS + 9-chunk MFMA.
// Block = 16 dsts (grid 6250), 512 thr (8 waves), 4 blocks/CU -> 32 waves/CU.
__global__ __launch_bounds__(512, 8) void rgcn_fused(
    const u32*  __restrict__ x32,     // x_bf rows of 64 u32
    const uint4* __restrict__ x16,    // x_bf rows of 16 uint4
    const uint4* __restrict__ Wt,     // 9 * 2048 uint4
    const u32*  __restrict__ locpre,  // [NBINS]
    const u32*  __restrict__ bsumx,   // [SCAN_NB] scanned block totals
    const u32*  __restrict__ spk,     // [E] sorted: src | local_bin<<17
    const float* __restrict__ bias,
    float* __restrict__ out) {
    extern __shared__ u32 ACC[];      // [128 bins][64 u32] + BND[132]
    u32* BND = ACC + BPB * 64;
    const int tid = threadIdx.x, w = tid >> 6, lane = tid & 63;
    const int g = lane >> 4, m = lane & 15;
    const int rowbase = blockIdx.x * RPB;

    // zero ACC + stage 129 bin boundaries
    uint4* az = reinterpret_cast<uint4*>(ACC);
#pragma unroll
    for (int i = 0; i < 4; ++i) az[tid + i * 512] = make_uint4(0u, 0u, 0u, 0u);
    if (tid <= BPB) {
        u32 idx = (u32)blockIdx.x * BPB + (u32)tid;
        BND[tid] = (idx >= (u32)NBINS) ? (u32)N_EDGES : (locpre[idx] + bsumx[idx >> 10]);
    }
    __syncthreads();

    // ---- phase 1: wave w aggregates local bins [w*16, w*16+16) (2 dsts)
    {
        const u32 elo = BND[w * 16];
        const u32 ehi = BND[w * 16 + 16];
        int cur_bin = -1, rcnt = 0;
        float a0 = 0.f, a1 = 0.f;
        for (u32 base = elo; base < ehi; base += 64) {
            const int bn = min(64, (int)(ehi - base));
            u32 pk = 0;
            if (lane < bn) pk = spk[base + lane];
            for (int j0 = 0; j0 < bn; j0 += 8) {
                const int lim = bn - j0;
                u32 pq[8], v[8];
#pragma unroll
                for (int q = 0; q < 8; ++q) {        // 8 independent row-gathers in flight
                    pq[q] = (u32)__shfl((int)pk, j0 + (q < lim ? q : 0));
                    v[q] = x32[(size_t)(pq[q] & 0x1FFFFu) * 64 + lane];
                }
#pragma unroll
                for (int q = 0; q < 8; ++q) {        // static index only
                    if (q < lim) {
                        const int b = (int)(pq[q] >> 17);
                        if (b != cur_bin) {          // wave-uniform
                            if (rcnt > 0) FLUSH2();
                            cur_bin = b; a0 = 0.f; a1 = 0.f; rcnt = 0;
                        }
                        a0 += __uint_as_float(v[q] << 16);
                        a1 += __uint_as_float(v[q] & 0xffff0000u);
                        ++rcnt;
                    }
                }
            }
        }
        if (rcnt > 0) FLUSH2();
    }
    __syncthreads();

    // ---- phase 2: 9-chunk MFMA. wave w owns cols [w*16,+16), 1 M-tile (16 rows).
    const uint4* ATq = reinterpret_cast<const uint4*>(ACC);
    f32x4 accv = (f32x4)0.f;
    union { uint4 u; bf16x8 h; } av, bv;
    const int colg = w * 16 + m;

    // chunk 0: root transform, A straight from global
#pragma unroll
    for (int ks = 0; ks < 4; ++ks) {
        bv.u = Wt[(size_t)colg * 16 + ks * 4 + g];
        av.u = x16[(size_t)(rowbase + m) * 16 + ks * 4 + g];
        accv = __builtin_amdgcn_mfma_f32_16x16x32_bf16(av.h, bv.h, accv, 0, 0, 0);
    }

    // chunks 1..8: A from swizzled LDS means
#pragma unroll 1
    for (int r = 0; r < 8; ++r) {
        const uint4* Wc = Wt + (size_t)(r + 1) * 2048;
#pragma unroll
        for (int ks = 0; ks < 4; ++ks) {
            bv.u = Wc[(size_t)colg * 16 + ks * 4 + g];
            av.u = ATq[(size_t)(m * 8 + r) * 16 + (u32)((ks * 4 + g) ^ m)];
            accv = __builtin_amdgcn_mfma_f32_16x16x32_bf16(av.h, bv.h, accv, 0, 0, 0);
        }
    }

    // epilogue: +bias, f32 store. C/D: col=m (B-col), row=g*4+j (A-row)
    {
        const float bb = bias[colg];
#pragma unroll
        for (int j = 0; j < 4; ++j)
            out[(size_t)(rowbase + g * 4 + j) * DIM + colg] = accv[j] + bb;
    }
}

// ---------------------------------------------------------------------------
extern "C" void kernel_launch(void* const* d_in, const int* in_sizes, int n_in,
                              void* d_out, int out_size, void* d_ws, size_t ws_size,
                              hipStream_t stream) {
    const float* x      = (const float*)d_in[0];
    const float* W      = (const float*)d_in[1];
    const float* W_root = (const float*)d_in[2];
    const float* bias   = (const float*)d_in[3];
    const int*   ei     = (const int*)d_in[4];   // [2][E]
    const int*   et     = (const int*)d_in[5];   // [E]
    float* out = (float*)d_out;

    char* ws = (char*)d_ws;
    uint4*          x_bf   = (uint4*)(ws);                        // 25,600,000
    unsigned short* Wt     = (unsigned short*)(ws + 25600000);    //    294,912
    u32*            locpre = (u32*)(ws + 25894912);               //  3,200,016
    u32*            hist   = (u32*)(ws + 29094928);               //  3,200,000
    u32*            bsumx  = (u32*)(ws + 32294928);               //      4,096
    u32*            rank   = (u32*)(ws + 32299024);               //  2,400,000
    u32*            spk    = (u32*)(ws + 34699024);               //  2,400,000
    // total 37,099,024 B

    hipMemsetAsync(hist, 0, (size_t)NBINS * 4, stream);
    prep<<<XBLOCKS + TBLOCKS + HBLOCKS, 256, 0, stream>>>(x, x_bf, W, W_root, Wt, ei, et, hist, rank);
    scanA<<<SCAN_NB, 256, 0, stream>>>(hist, locpre, bsumx);
    scanB<<<1, 256, 0, stream>>>(bsumx, SCAN_NB);
    reorder<<<HBLOCKS, 256, 0, stream>>>(ei, et, locpre, bsumx, rank, spk);
    rgcn_fused<<<FBLOCKS, 512, LDS_BYTES, stream>>>((const u32*)x_bf, x_bf, (const uint4*)Wt,
                                                    locpre, bsumx, spk, bias, out);
}

// Round 10
// 224.313 us; speedup vs baseline: 1.3417x; 1.3417x over previous
//
#include <hip/hip_runtime.h>

#define N_NODES 100000
#define N_EDGES 600000
#define DIM 128
#define NUM_RELS 8
#define NBINS (NUM_RELS * N_NODES)          // node-major: key = dst*8 + r
#define SCAN_NB ((NBINS + 1023) / 1024)     // 782
#define XBLOCKS 6250
#define TBLOCKS 576
#define HBLOCKS ((N_EDGES + 255) / 256)

#define RPB 32                               // dsts per fused block (R7 geometry)
#define BPB (RPB * NUM_RELS)                 // 256 bins/block
#define FBLOCKS (N_NODES / RPB)              // 3125 exact
#define LDS_BYTES ((BPB * 64 + 260) * 4)     // 66,576 B -> 2 blocks/CU

typedef unsigned int u32;
typedef __attribute__((ext_vector_type(8))) short bf16x8;
typedef __attribute__((ext_vector_type(4))) float f32x4;

__device__ __forceinline__ u32 pack2_bf16_rn(float lo, float hi) {
    u32 a = __float_as_uint(lo);
    u32 b = __float_as_uint(hi);
    a += 0x7fffu + ((a >> 16) & 1u);
    b += 0x7fffu + ((b >> 16) & 1u);
    return (a >> 16) | (b & 0xffff0000u);
}

// ---------------------------------------------------------------------------
// prep = convert_x | transpose_w | hist+rank
__global__ __launch_bounds__(256) void prep(
    const float* __restrict__ x, uint4* __restrict__ x_bf,
    const float* __restrict__ W, const float* __restrict__ W_root,
    unsigned short* __restrict__ Wt,
    const int* __restrict__ ei, const int* __restrict__ et,
    u32* __restrict__ hist, u32* __restrict__ rank) {
    int b = blockIdx.x, tid = threadIdx.x;
    if (b < XBLOCKS) {
        int t = b * 256 + tid;
        const float4* p = reinterpret_cast<const float4*>(x) + (size_t)t * 2;
        float4 v0 = p[0], v1 = p[1];
        uint4 o;
        o.x = pack2_bf16_rn(v0.x, v0.y);
        o.y = pack2_bf16_rn(v0.z, v0.w);
        o.z = pack2_bf16_rn(v1.x, v1.y);
        o.w = pack2_bf16_rn(v1.z, v1.w);
        x_bf[t] = o;
    } else if (b < XBLOCKS + TBLOCKS) {
        int t = (b - XBLOCKS) * 256 + tid;
        int c  = t >> 14;
        int kn = t & 16383;
        int k = kn >> 7, n = kn & 127;
        float v = (c == 0) ? W_root[kn] : W[(size_t)(c - 1) * DIM * DIM + kn];
        u32 bb = __float_as_uint(v);
        bb += 0x7fffu + ((bb >> 16) & 1u);
        Wt[(size_t)c * 16384 + n * 128 + k] = (unsigned short)(bb >> 16);
    } else {
        int e = (b - XBLOCKS - TBLOCKS) * 256 + tid;
        if (e < N_EDGES) {
            int dst = ei[N_EDGES + e];
            int r   = et[e];
            rank[e] = atomicAdd(&hist[(size_t)dst * NUM_RELS + r], 1u);
        }
    }
}

// ---------------------------------------------------------------------------
// scanA: block-local exclusive prefix of hist -> locpre, block totals -> bsum
__global__ __launch_bounds__(256) void scanA(const u32* __restrict__ hist,
                                             u32* __restrict__ locpre,
                                             u32* __restrict__ bsum) {
    __shared__ u32 sh[256];
    int t = threadIdx.x;
    size_t base = (size_t)blockIdx.x * 1024 + t * 4;
    u32 v[4]; u32 s = 0;
#pragma unroll
    for (int j = 0; j < 4; ++j) { size_t i = base + j; v[j] = (i < NBINS) ? hist[i] : 0; s += v[j]; }
    sh[t] = s; __syncthreads();
    for (int off = 1; off < 256; off <<= 1) {
        u32 add = (t >= off) ? sh[t - off] : 0;
        __syncthreads();
        sh[t] += add;
        __syncthreads();
    }
    u32 run = (t > 0) ? sh[t - 1] : 0;
#pragma unroll
    for (int j = 0; j < 4; ++j) {
        size_t i = base + j;
        if (i < NBINS) locpre[i] = run;
        run += v[j];
    }
    if (t == 255) bsum[blockIdx.x] = sh[255];
}

// scanB: 1-block exclusive scan of the 782 block totals
__global__ __launch_bounds__(256) void scanB(u32* __restrict__ bsum, int nb) {
    __shared__ u32 sh[256];
    int t = threadIdx.x;
    u32 v[4]; u32 s = 0;
#pragma unroll
    for (int j = 0; j < 4; ++j) { int i = t * 4 + j; v[j] = (i < nb) ? bsum[i] : 0; s += v[j]; }
    sh[t] = s; __syncthreads();
    for (int off = 1; off < 256; off <<= 1) {
        u32 add = (t >= off) ? sh[t - off] : 0;
        __syncthreads();
        sh[t] += add;
        __syncthreads();
    }
    u32 run = (t > 0) ? sh[t - 1] : 0;
#pragma unroll
    for (int j = 0; j < 4; ++j) { int i = t * 4 + j; if (i < nb) bsum[i] = run; run += v[j]; }
}

// pos = locpre[key] + bsumx[key>>10] + rank; spk = src | local_bin<<17
__global__ __launch_bounds__(256) void reorder(const int* __restrict__ ei,
                                               const int* __restrict__ et,
                                               const u32* __restrict__ locpre,
                                               const u32* __restrict__ bsumx,
                                               const u32* __restrict__ rank,
                                               u32* __restrict__ spk) {
    int e = blockIdx.x * 256 + threadIdx.x;
    if (e >= N_EDGES) return;
    int dst = ei[N_EDGES + e];
    int r   = et[e];
    size_t key = (size_t)dst * NUM_RELS + r;
    u32 pos = locpre[key] + bsumx[key >> 10] + rank[e];
    u32 bin = (u32)((dst & (RPB - 1)) * NUM_RELS + r);
    spk[pos] = (u32)ei[e] | (bin << 17);
}

// ---------------------------------------------------------------------------
// write mean row (bf16-packed, granule-XOR-swizzled) for the finished bin
#define FLUSH2() do { \
    float sc_ = __builtin_amdgcn_rcpf((float)rcnt); \
    ACC[(u32)cur_bin * 64u + ((((lane >> 2) ^ (((u32)cur_bin >> 3) & 15u)) << 2) | (u32)(lane & 3))] = \
        pack2_bf16_rn(a0 * sc_, a1 * sc_); \
} while (0)

// issue 8 independent row-gathers for batch starting at J (static names only)
#define LOADB(J, PQ, V) do { \
    _Pragma("unroll") \
    for (int q_ = 0; q_ < 8; ++q_) { \
        int idx_ = (J) + (q_ < bn - (J) ? q_ : 0); \
        PQ[q_] = (u32)__shfl((int)pk, idx_); \
        V[q_] = x32[(size_t)(PQ[q_] & 0x1FFFFu) * 64 + lane]; \
    } \
} while (0)

// accumulate batch starting at J through the run state machine
#define ACCB(J, PQ, V) do { \
    _Pragma("unroll") \
    for (int q_ = 0; q_ < 8; ++q_) { \
        if (q_ < bn - (J)) { \
            const int b_ = (int)(PQ[q_] >> 17); \
            if (b_ != cur_bin) { \
                if (rcnt > 0) FLUSH2(); \
                cur_bin = b_; a0 = 0.f; a1 = 0.f; rcnt = 0; \
            } \
            a0 += __uint_as_float(V[q_] << 16); \
            a1 += __uint_as_float(V[q_] & 0xffff0000u); \
            ++rcnt; \
        } \
    } \
} while (0)

// Fused RGCN: sorted-run register aggregation into 64KB LDS + 9-chunk MFMA.
// R7 geometry: block = 32 dsts (grid 3125), 512 thr (8 waves), 2 blocks/CU.
// New: ping-pong double-buffered 8-deep gather batches (16 outstanding).
__global__ __launch_bounds__(512, 4) void rgcn_fused(
    const u32*  __restrict__ x32,     // x_bf rows of 64 u32
    const uint4* __restrict__ x16,    // x_bf rows of 16 uint4
    const uint4* __restrict__ Wt,     // 9 * 2048 uint4
    const u32*  __restrict__ locpre,  // [NBINS]
    const u32*  __restrict__ bsumx,   // [SCAN_NB]
    const u32*  __restrict__ spk,     // [E] sorted: src | local_bin<<17
    const float* __restrict__ bias,
    float* __restrict__ out) {
    extern __shared__ u32 ACC[];      // [256 bins][64 u32] + BND[257]
    u32* BND = ACC + BPB * 64;
    const int tid = threadIdx.x, w = tid >> 6, lane = tid & 63;
    const int g = lane >> 4, m = lane & 15;
    const int rowbase = blockIdx.x * RPB;

    // zero ACC + stage 257 bin boundaries
    uint4* az = reinterpret_cast<uint4*>(ACC);
#pragma unroll
    for (int i = 0; i < 8; ++i) az[tid + i * 512] = make_uint4(0u, 0u, 0u, 0u);
    if (tid <= BPB) {
        u32 idx = (u32)blockIdx.x * BPB + (u32)tid;
        BND[tid] = (idx >= (u32)NBINS) ? (u32)N_EDGES : (locpre[idx] + bsumx[idx >> 10]);
    }
    __syncthreads();

    // ---- phase 1: wave w aggregates local bins [w*32, w*32+32) (4 dsts)
    {
        const u32 elo = BND[w * 32];
        const u32 ehi = BND[w * 32 + 32];
        int cur_bin = -1, rcnt = 0;
        float a0 = 0.f, a1 = 0.f;
        for (u32 base = elo; base < ehi; base += 64) {
            const int bn = min(64, (int)(ehi - base));
            u32 pk = 0;
            if (lane < bn) pk = spk[base + lane];
            u32 pqA[8], vA[8], pqB[8], vB[8];
            LOADB(0, pqA, vA);
            for (int j0 = 0; j0 < 64; j0 += 16) {
                if (j0 >= bn) break;                 // uniform
                if (j0 + 8 < bn) LOADB(j0 + 8, pqB, vB);
                ACCB(j0, pqA, vA);
                if (j0 + 8 < bn) {
                    if (j0 + 16 < bn) LOADB(j0 + 16, pqA, vA);
                    ACCB(j0 + 8, pqB, vB);
                }
            }
        }
        if (rcnt > 0) FLUSH2();
    }
    __syncthreads();

    // ---- phase 2: 9-chunk MFMA. wave w owns cols [w*16,+16), 2 M-tiles.
    const uint4* ATq = reinterpret_cast<const uint4*>(ACC);
    f32x4 accv[2];
    accv[0] = (f32x4)0.f; accv[1] = (f32x4)0.f;
    union { uint4 u; bf16x8 h; } av, bv;
    const int colg = w * 16 + m;

    // chunk 0: root transform, A straight from global
#pragma unroll
    for (int ks = 0; ks < 4; ++ks) {
        bv.u = Wt[(size_t)colg * 16 + ks * 4 + g];
        bf16x8 bf = bv.h;
#pragma unroll
        for (int mt = 0; mt < 2; ++mt) {
            av.u = x16[(size_t)(rowbase + mt * 16 + m) * 16 + ks * 4 + g];
            accv[mt] = __builtin_amdgcn_mfma_f32_16x16x32_bf16(av.h, bf, accv[mt], 0, 0, 0);
        }
    }

    // chunks 1..8: A from swizzled LDS means
#pragma unroll 1
    for (int r = 0; r < 8; ++r) {
        const uint4* Wc = Wt + (size_t)(r + 1) * 2048;
#pragma unroll
        for (int ks = 0; ks < 4; ++ks) {
            bv.u = Wc[(size_t)colg * 16 + ks * 4 + g];
            bf16x8 bf = bv.h;
#pragma unroll
            for (int mt = 0; mt < 2; ++mt) {
                av.u = ATq[(size_t)((mt * 16 + m) * 8 + r) * 16 + (u32)((ks * 4 + g) ^ m)];
                accv[mt] = __builtin_amdgcn_mfma_f32_16x16x32_bf16(av.h, bf, accv[mt], 0, 0, 0);
            }
        }
    }

    // epilogue: +bias, f32 store. C/D: col=m (B-col), row=g*4+j (A-row)
    {
        const float bb = bias[colg];
#pragma unroll
        for (int mt = 0; mt < 2; ++mt)
#pragma unroll
            for (int j = 0; j < 4; ++j)
                out[(size_t)(rowbase + mt * 16 + g * 4 + j) * DIM + colg] = accv[mt][j] + bb;
    }
}

// ---------------------------------------------------------------------------
extern "C" void kernel_launch(void* const* d_in, const int* in_sizes, int n_in,
                              void* d_out, int out_size, void* d_ws, size_t ws_size,
                              hipStream_t stream) {
    const float* x      = (const float*)d_in[0];
    const float* W      = (const float*)d_in[1];
    const float* W_root = (const float*)d_in[2];
    const float* bias   = (const float*)d_in[3];
    const int*   ei     = (const int*)d_in[4];   // [2][E]
    const int*   et     = (const int*)d_in[5];   // [E]
    float* out = (float*)d_out;

    char* ws = (char*)d_ws;
    uint4*          x_bf   = (uint4*)(ws);                        // 25,600,000
    unsigned short* Wt     = (unsigned short*)(ws + 25600000);    //    294,912
    u32*            locpre = (u32*)(ws + 25894912);               //  3,200,016
    u32*            hist   = (u32*)(ws + 29094928);               //  3,200,000
    u32*            bsumx  = (u32*)(ws + 32294928);               //      4,096
    u32*            rank   = (u32*)(ws + 32299024);               //  2,400,000
    u32*            spk    = (u32*)(ws + 34699024);               //  2,400,000
    // total 37,099,024 B

    hipMemsetAsync(hist, 0, (size_t)NBINS * 4, stream);
    prep<<<XBLOCKS + TBLOCKS + HBLOCKS, 256, 0, stream>>>(x, x_bf, W, W_root, Wt, ei, et, hist, rank);
    scanA<<<SCAN_NB, 256, 0, stream>>>(hist, locpre, bsumx);
    scanB<<<1, 256, 0, stream>>>(bsumx, SCAN_NB);
    reorder<<<HBLOCKS, 256, 0, stream>>>(ei, et, locpre, bsumx, rank, spk);
    rgcn_fused<<<FBLOCKS, 512, LDS_BYTES, stream>>>((const u32*)x_bf, x_bf, (const uint4*)Wt,
                                                    locpre, bsumx, spk, bias, out);
}